// Round 2
// baseline (676.557 us; speedup 1.0000x reference)
//
#include <hip/hip_runtime.h>
#include <hip/hip_bf16.h>

typedef __bf16 bf16;
typedef bf16 bf16x4 __attribute__((ext_vector_type(4)));
typedef bf16 bf16x8 __attribute__((ext_vector_type(8)));
typedef float f32x4 __attribute__((ext_vector_type(4)));

// LDS element (short) offsets; rows padded +8 elements (16B) to break bank conflicts.
#define XS_OFF   0      // x bf16 [128][72]       (phase A)  -> Kcm [64][136] (phase C)
#define WQ_OFF   9216   // WqT bf16 [64][72]      (phase A)  -> Krm [128][72] (phase C, spans WQ+WK)
#define WK_OFF   13824  // WkT bf16 [64][72]
#define WR_OFF   18432  // WrT bf16 [64][72]      (phase A)  -> A_tile bf16 [32][136] (phase C)
#define Q_OFF    23040  // Q bf16 [128][72]       (all phases)
#define KRM_OFF  9216
#define KCM_OFF  0
#define AT_OFF   18432
#define RS64     72
#define RS128    136

__device__ inline short f2bs(float v) { bf16 b = (bf16)v; return __builtin_bit_cast(short, b); }
__device__ inline bf16x8 ldfrag(const short* s) {
  uint4 u = *(const uint4*)s;
  return __builtin_bit_cast(bf16x8, u);
}
__device__ inline f32x4 mfma16(bf16x8 a, bf16x8 b, f32x4 c) {
  return __builtin_amdgcn_mfma_f32_16x16x32_bf16(a, b, c, 0, 0, 0);
}

__global__ __launch_bounds__(256) void fused_mha_kernel(
    const float* __restrict__ x, const float* __restrict__ qw,
    const float* __restrict__ kw, const float* __restrict__ rw,
    const float* __restrict__ gamma, const float* __restrict__ beta,
    float* __restrict__ out)
{
  __shared__ __align__(16) short smem[32256];  // 64512 B

  const int bx   = blockIdx.x;          // h*1024 + b
  const int h    = bx >> 10;
  const int b    = bx & 1023;
  const int tid  = threadIdx.x;
  const int w    = tid >> 6;            // wave 0..3
  const int lane = tid & 63;
  const int q    = lane >> 4;           // quad 0..3
  const int l15  = lane & 15;

  // ---- Phase A: stage x (bf16) and the three transposed weight tiles ----
  {
    const float4* xg = (const float4*)(x + (size_t)b * 8192);
    for (int r = 0; r < 8; ++r) {
      int idx4 = r * 256 + tid;             // 2048 float4s
      float4 v = xg[idx4];
      int f = idx4 >> 4;
      int i = (idx4 & 15) * 4;
      bf16x4 t;
      t[0] = (bf16)v.x; t[1] = (bf16)v.y; t[2] = (bf16)v.z; t[3] = (bf16)v.w;
      *(bf16x4*)(void*)&smem[XS_OFF + f * RS64 + i] = t;
    }
    const float* wsrc[3] = {qw, kw, rw};
    const int   woff[3] = {WQ_OFF, WK_OFF, WR_OFF};
    int wi = tid >> 2;                   // DIN row 0..63
    int dg = (tid & 3) * 16;             // d-group
    for (int s = 0; s < 3; ++s) {
      const float* base = wsrc[s] + (size_t)wi * 512 + h * 64 + dg;
      short* dst = smem + woff[s];
      for (int u = 0; u < 4; ++u) {
        float4 v = *(const float4*)(base + u * 4);
        int d0 = dg + u * 4;
        dst[(d0 + 0) * RS64 + wi] = f2bs(v.x);
        dst[(d0 + 1) * RS64 + wi] = f2bs(v.y);
        dst[(d0 + 2) * RS64 + wi] = f2bs(v.z);
        dst[(d0 + 3) * RS64 + wi] = f2bs(v.w);
      }
    }
  }
  __syncthreads();

  // Projection: M=128 (wave w owns M-tiles 2w,2w+1), N=64, K=64
  f32x4 acc[8];
  auto proj = [&](int wt) {
    for (int t = 0; t < 8; ++t) acc[t] = (f32x4){0.f, 0.f, 0.f, 0.f};
    for (int ks = 0; ks < 2; ++ks) {
      int ke = ks * 32 + q * 8;
      bf16x8 a0 = ldfrag(smem + XS_OFF + ((2 * w + 0) * 16 + l15) * RS64 + ke);
      bf16x8 a1 = ldfrag(smem + XS_OFF + ((2 * w + 1) * 16 + l15) * RS64 + ke);
      for (int nt = 0; nt < 4; ++nt) {
        bf16x8 bb = ldfrag(smem + wt + (nt * 16 + l15) * RS64 + ke);
        acc[nt]     = mfma16(a0, bb, acc[nt]);
        acc[4 + nt] = mfma16(a1, bb, acc[4 + nt]);
      }
    }
  };

  // ---- R = x*Wr -> global (output 1, raw) ----
  proj(WR_OFF);
  {
    float* outR = out + 67108864 + (size_t)bx * 8192;
    for (int t = 0; t < 8; ++t) {
      int mt2 = t >> 2, nt = t & 3;
      int row0 = (2 * w + mt2) * 16 + q * 4;
      int col  = nt * 16 + l15;
      for (int r = 0; r < 4; ++r) outR[(row0 + r) * 64 + col] = acc[t][r];
    }
  }

  // ---- Q = x*Wq -> LDS bf16 row-major ----
  proj(WQ_OFF);
  for (int t = 0; t < 8; ++t) {
    int mt2 = t >> 2, nt = t & 3;
    int row0 = (2 * w + mt2) * 16 + q * 4;
    int col  = nt * 16 + l15;
    for (int r = 0; r < 4; ++r) smem[Q_OFF + (row0 + r) * RS64 + col] = f2bs(acc[t][r]);
  }

  // ---- K = x*Wk (V==K). Store row-major (B-op of S) and col-major (B-op of O). ----
  proj(WK_OFF);
  __syncthreads();   // everyone done reading xs / weights
  for (int t = 0; t < 8; ++t) {
    int mt2 = t >> 2, nt = t & 3;
    int row0 = (2 * w + mt2) * 16 + q * 4;  // g
    int col  = nt * 16 + l15;               // d
    for (int r = 0; r < 4; ++r) {
      short kb = f2bs(acc[t][r]);
      smem[KRM_OFF + (row0 + r) * RS64 + col]  = kb;   // Krm[g][d]
      smem[KCM_OFF + col * RS128 + (row0 + r)] = kb;   // Kcm[d][g]
    }
  }
  __syncthreads();

  // Per-lane gamma/beta fragments for register-resident LN (d = j*16 + l15)
  float gam[4], bet[4];
  for (int j = 0; j < 4; ++j) { gam[j] = gamma[j * 16 + l15]; bet[j] = beta[j * 16 + l15]; }

  // ---- Phase C: 4 chunks of 32 f-rows: S -> sigmoid -> O (registers) -> LN -> store ----
  float* out0 = out + (size_t)bx * 8192;
  for (int c = 0; c < 4; ++c) {
    // S = Q*K^T (M=32 chunk, N=128): wave w: M-tile (w&1), N-tiles 4*(w>>1)..+3
    f32x4 sacc[4];
    for (int j = 0; j < 4; ++j) sacc[j] = (f32x4){0.f, 0.f, 0.f, 0.f};
    int mtg = 2 * c + (w & 1);
    int ntb = (w >> 1) * 4;
    for (int ks = 0; ks < 2; ++ks) {
      int ke = ks * 32 + q * 8;
      bf16x8 aS = ldfrag(smem + Q_OFF + (mtg * 16 + l15) * RS64 + ke);
      for (int j = 0; j < 4; ++j) {
        bf16x8 bS = ldfrag(smem + KRM_OFF + ((ntb + j) * 16 + l15) * RS64 + ke);
        sacc[j] = mfma16(aS, bS, sacc[j]);
      }
    }
    int rowA0 = (w & 1) * 16 + q * 4;
    for (int j = 0; j < 4; ++j)
      for (int r = 0; r < 4; ++r) {
        float s = sacc[j][r] * 0.125f;            // /sqrt(64)
        float a = 1.0f / (1.0f + __expf(-s));     // sigmoid
        smem[AT_OFF + (rowA0 + r) * RS128 + (ntb + j) * 16 + l15] = f2bs(a);
      }
    __syncthreads();

    // O = A*V (M=16 per wave, N=64 full, K=128): waves 0,1 only; O stays in registers.
    if (w < 2) {
      f32x4 oacc[4];
      for (int j = 0; j < 4; ++j) oacc[j] = (f32x4){0.f, 0.f, 0.f, 0.f};
      for (int ks = 0; ks < 4; ++ks) {
        int ke = ks * 32 + q * 8;
        bf16x8 aO = ldfrag(smem + AT_OFF + (w * 16 + l15) * RS128 + ke);
        for (int j = 0; j < 4; ++j) {
          bf16x8 bO = ldfrag(smem + KCM_OFF + (j * 16 + l15) * RS128 + ke);
          oacc[j] = mfma16(aO, bO, oacc[j]);
        }
      }
      // Register LayerNorm: lane holds d = {j*16+l15} for rows q*4+r of M-tile w.
      // Row's 64 d-values live in the 16 lanes of this quad -> xor 1,2,4,8 reduce.
      for (int r = 0; r < 4; ++r) {
        float v0 = oacc[0][r], v1 = oacc[1][r], v2 = oacc[2][r], v3 = oacc[3][r];
        float s1 = v0 + v1 + v2 + v3;
        float s2 = v0 * v0 + v1 * v1 + v2 * v2 + v3 * v3;
        s1 += __shfl_xor(s1, 1);  s2 += __shfl_xor(s2, 1);
        s1 += __shfl_xor(s1, 2);  s2 += __shfl_xor(s2, 2);
        s1 += __shfl_xor(s1, 4);  s2 += __shfl_xor(s2, 4);
        s1 += __shfl_xor(s1, 8);  s2 += __shfl_xor(s2, 8);
        float mean = s1 * 0.015625f;
        float var  = s2 * 0.015625f - mean * mean;
        float rstd = rsqrtf(var + 1e-3f);
        int gf = c * 32 + w * 16 + q * 4 + r;
        float* dst = out0 + gf * 64 + l15;
        dst[0]  = (v0 - mean) * rstd * gam[0] + bet[0];
        dst[16] = (v1 - mean) * rstd * gam[1] + bet[1];
        dst[32] = (v2 - mean) * rstd * gam[2] + bet[2];
        dst[48] = (v3 - mean) * rstd * gam[3] + bet[3];
      }
    }
    __syncthreads();   // A_tile reads complete before next chunk overwrites it
  }
}

extern "C" void kernel_launch(void* const* d_in, const int* in_sizes, int n_in,
                              void* d_out, int out_size, void* d_ws, size_t ws_size,
                              hipStream_t stream) {
  const float* x     = (const float*)d_in[0];
  const float* qw    = (const float*)d_in[1];
  const float* kw    = (const float*)d_in[2];
  const float* rw    = (const float*)d_in[3];
  const float* gamma = (const float*)d_in[4];
  const float* beta  = (const float*)d_in[5];
  float* out = (float*)d_out;
  fused_mha_kernel<<<dim3(8192), dim3(256), 0, stream>>>(x, qw, kw, rw, gamma, beta, out);
}